// Round 4
// baseline (1115.630 us; speedup 1.0000x reference)
//
#include <hip/hip_runtime.h>
#include <math.h>
#include <float.h>

#define EPSV 1e-8f
#define MASK_FILL 1000000000.0f
constexpr int D = 64;

// ---------------------------------------------------------------------------
// Kernel 1: normalize codebook rows.
//   cb  = codebook/(||codebook||+eps)   natural [K][64] (for the gather)
//   cbt = cb/(||cb||+eps), stored tile-transposed (g-major) per 64-code tile:
//         float4 slot = tile*1024 + g*64 + c   (g = dim/4, c = code in tile)
//   Read pattern buf[g*64+lane] measured ZERO bank conflicts in R1, and the
//   per-lane address is base + g*1024B -> compile-time ds_read offsets.
// ---------------------------------------------------------------------------
__global__ __launch_bounds__(256) void k_cb(const float* __restrict__ cbin,
                                            float* __restrict__ cb,
                                            float4* __restrict__ cbt) {
    __shared__ float tile[16 * 64 * 4];  // [g][c][4] = 16 KB
    const int t = threadIdx.x;
    const int wv = t >> 6, lane = t & 63;    // lane = dim
    const int tileRow0 = blockIdx.x * 64;

    for (int j = 0; j < 16; ++j) {
        const int c = wv * 16 + j;           // code within tile
        const int row = tileRow0 + c;
        float v = cbin[row * D + lane];
        float ss = v * v;
        #pragma unroll
        for (int off = 32; off; off >>= 1) ss += __shfl_xor(ss, off, 64);
        const float c1 = v / (sqrtf(ss) + EPSV);
        cb[row * D + lane] = c1;
        float ss2 = c1 * c1;
        #pragma unroll
        for (int off = 32; off; off >>= 1) ss2 += __shfl_xor(ss2, off, 64);
        const float c2 = c1 / (sqrtf(ss2) + EPSV);
        // transposed store: float offset (d/4)*256 + c*4 + (d%4)
        tile[(lane >> 2) * 256 + c * 4 + (lane & 3)] = c2;
    }
    __syncthreads();
    float4* dst = cbt + (size_t)blockIdx.x * 1024;
    const float4* srcT = (const float4*)tile;
    #pragma unroll
    for (int i = 0; i < 4; ++i) dst[i * 256 + t] = srcT[i * 256 + t];
}

// ---------------------------------------------------------------------------
// Kernel 2: normalize x rows -> x_n (written straight into d_out region 2)
// ---------------------------------------------------------------------------
__global__ __launch_bounds__(256) void k_x(const float* __restrict__ xin,
                                           float* __restrict__ xn) {
    const int t = threadIdx.x;
    const int wv = t >> 6, lane = t & 63;
    const int row = blockIdx.x * 4 + wv;
    float v = xin[row * D + lane];
    float ss = v * v;
    #pragma unroll
    for (int off = 32; off; off >>= 1) ss += __shfl_xor(ss, off, 64);
    xn[row * D + lane] = v / (sqrtf(ss) + EPSV);
}

// ---------------------------------------------------------------------------
// Kernel 3: distance scan. lane<->code, 8 rows/wave, K-split 2, 4 blocks/CU.
//   cb tile: chunked ds_read_b128 at immediate offsets (16 VGPR live/chunk)
//   x row  : wave-uniform pointer -> compiler-scheduled scalar loads
//   no inline asm: compiler keeps fine-grained lgkmcnt counts
// ---------------------------------------------------------------------------
__global__ __launch_bounds__(256, 4) void k_main(const float* __restrict__ xn,
                                                 const float4* __restrict__ cbt,
                                                 const int* __restrict__ mask,
                                                 const int* __restrict__ training,
                                                 float* __restrict__ pd,
                                                 int* __restrict__ pi,
                                                 int B, int K) {
    __shared__ float4 buf[2][1024];   // 2 x 16 KB double buffer, [g][c] tiles
    const int t = threadIdx.x;
    const int wv = t >> 6, lane = t & 63;
    const int half = blockIdx.x & 1;
    const int row0 = (blockIdx.x >> 1) * 32;
    const int tr = training[0];
    const int nt = (K / 2) / 64;               // 128 tiles per half
    const int t0 = half * nt;

#define STAGE(bsel, tile_) do {                                                   \
    const float4* gs_ = cbt + (size_t)(tile_) * 1024 + t;                         \
    __builtin_amdgcn_global_load_lds(                                             \
        (const __attribute__((address_space(1))) void*)(gs_),                     \
        (__attribute__((address_space(3))) void*)(&buf[bsel][wv * 64]), 16, 0, 0);\
    __builtin_amdgcn_global_load_lds(                                             \
        (const __attribute__((address_space(1))) void*)(gs_ + 256),               \
        (__attribute__((address_space(3))) void*)(&buf[bsel][256 + wv * 64]), 16, 0, 0);\
    __builtin_amdgcn_global_load_lds(                                             \
        (const __attribute__((address_space(1))) void*)(gs_ + 512),               \
        (__attribute__((address_space(3))) void*)(&buf[bsel][512 + wv * 64]), 16, 0, 0);\
    __builtin_amdgcn_global_load_lds(                                             \
        (const __attribute__((address_space(1))) void*)(gs_ + 768),               \
        (__attribute__((address_space(3))) void*)(&buf[bsel][768 + wv * 64]), 16, 0, 0);\
} while (0)

    const int wvu = __builtin_amdgcn_readfirstlane(wv);
    const float* xwave = xn + (size_t)(row0 + wvu * 8) * 64;   // uniform row base
    const int* mwave = mask + (size_t)(row0 + wv * 8) * K + lane;

    float best[8];
    int bidx[8];
    #pragma unroll
    for (int r = 0; r < 8; ++r) { best[r] = FLT_MAX; bidx[r] = 0; }

    STAGE(0, t0);
    int cur = 0;
    for (int tt = 0; tt < nt; ++tt) {
        __syncthreads();                 // barrier drains vmcnt -> buf[cur] ready
        if (tt + 1 < nt) STAGE(cur ^ 1, t0 + tt + 1);

        const int gk = (t0 + tt) * 64;   // global code base of this tile
        int m[8];
        #pragma unroll
        for (int r = 0; r < 8; ++r) m[r] = mwave[(size_t)r * K + gk];

        const float4* bp = buf[cur] + lane;
        float sim[8];
        #pragma unroll
        for (int r = 0; r < 8; ++r) sim[r] = 0.f;

        #pragma unroll
        for (int c = 0; c < 4; ++c) {
            const float4 cv0 = bp[(c * 4 + 0) * 64];
            const float4 cv1 = bp[(c * 4 + 1) * 64];
            const float4 cv2 = bp[(c * 4 + 2) * 64];
            const float4 cv3 = bp[(c * 4 + 3) * 64];
            #pragma unroll
            for (int r = 0; r < 8; ++r) {
                const float* xp = xwave + r * 64 + c * 16;
                float s = sim[r];
                s = fmaf(xp[0],  cv0.x, s);  s = fmaf(xp[1],  cv0.y, s);
                s = fmaf(xp[2],  cv0.z, s);  s = fmaf(xp[3],  cv0.w, s);
                s = fmaf(xp[4],  cv1.x, s);  s = fmaf(xp[5],  cv1.y, s);
                s = fmaf(xp[6],  cv1.z, s);  s = fmaf(xp[7],  cv1.w, s);
                s = fmaf(xp[8],  cv2.x, s);  s = fmaf(xp[9],  cv2.y, s);
                s = fmaf(xp[10], cv2.z, s);  s = fmaf(xp[11], cv2.w, s);
                s = fmaf(xp[12], cv3.x, s);  s = fmaf(xp[13], cv3.y, s);
                s = fmaf(xp[14], cv3.z, s);  s = fmaf(xp[15], cv3.w, s);
                sim[r] = s;
            }
        }

        const int kk = gk + lane;
        #pragma unroll
        for (int r = 0; r < 8; ++r) {
            const float dist = (m[r] != 0 || tr == 0) ? -sim[r] : MASK_FILL;
            if (dist < best[r]) { best[r] = dist; bidx[r] = kk; }  // first-min
        }
        cur ^= 1;
    }

    #pragma unroll
    for (int r = 0; r < 8; ++r) {
        float b = best[r];
        int bi = bidx[r];
        #pragma unroll
        for (int off = 32; off; off >>= 1) {
            const float ob = __shfl_xor(b, off, 64);
            const int   oi = __shfl_xor(bi, off, 64);
            if (ob < b || (ob == b && oi < bi)) { b = ob; bi = oi; }
        }
        if (lane == 0) {
            const int grow = row0 + wv * 8 + r;
            pd[(size_t)half * B + grow] = b;
            pi[(size_t)half * B + grow] = bi;
        }
    }
#undef STAGE
}

// ---------------------------------------------------------------------------
// Kernel 4: combine the two K-halves, gather z, write zq/z/indices
// ---------------------------------------------------------------------------
__global__ __launch_bounds__(256) void k_reduce(const float* __restrict__ xn,
                                                const float* __restrict__ cb,
                                                const float* __restrict__ pd,
                                                const int* __restrict__ pi,
                                                float* __restrict__ out, int B) {
    const int t = threadIdx.x;
    const int wv = t >> 6, lane = t & 63;
    const int row = blockIdx.x * 4 + wv;
    const float d0 = pd[row], d1 = pd[B + row];
    const int   i0 = pi[row], i1 = pi[B + row];
    const int   bi = (d1 < d0) ? i1 : i0;      // tie -> half 0 (lower index)
    const float zv  = cb[(size_t)bi * D + lane];
    const float xnv = xn[(size_t)row * D + lane];
    const float zq  = xnv + (zv - xnv);        // literal straight-through math
    float* out_zq  = out;
    float* out_z   = out + (size_t)B * D;
    float* out_idx = out + (size_t)3 * B * D;
    out_zq[(size_t)row * D + lane] = zq;
    out_z [(size_t)row * D + lane] = zv;
    if (lane == 0) out_idx[row] = (float)bi;
}

extern "C" void kernel_launch(void* const* d_in, const int* in_sizes, int n_in,
                              void* d_out, int out_size, void* d_ws, size_t ws_size,
                              hipStream_t stream) {
    const float* x    = (const float*)d_in[0];
    const float* cbin = (const float*)d_in[1];
    const int* mask   = (const int*)d_in[2];
    const int* train  = (const int*)d_in[3];
    const int B = in_sizes[0] / D;   // 16384
    const int K = in_sizes[1] / D;   // 16384
    float* out = (float*)d_out;

    float* ws   = (float*)d_ws;
    float* cb   = ws;                              // K*64 f32 = 4 MB
    float* cbtf = ws + (size_t)K * D;              // 4 MB, g-major tiles
    float* pd   = ws + (size_t)2 * K * D;          // 2*B floats
    int*   pi   = (int*)(ws + (size_t)2 * K * D + 2 * B);

    float* out_xn = out + (size_t)2 * B * D;

    k_cb    <<<K / 64, 256, 0, stream>>>(cbin, cb, (float4*)cbtf);
    k_x     <<<B / 4,  256, 0, stream>>>(x, out_xn);
    k_main  <<<(B / 32) * 2, 256, 0, stream>>>(out_xn, (const float4*)cbtf, mask,
                                               train, pd, pi, B, K);
    k_reduce<<<B / 4,  256, 0, stream>>>(out_xn, cb, pd, pi, out, B);
}

// Round 5
// 482.101 us; speedup vs baseline: 2.3141x; 2.3141x over previous
//
#include <hip/hip_runtime.h>
#include <math.h>
#include <float.h>

#define EPSV 1e-8f
constexpr int D = 64;

typedef __attribute__((ext_vector_type(8)))  short short8;
typedef __attribute__((ext_vector_type(16))) float f32x16;

static __device__ __forceinline__ unsigned short f2bf(float f) {
    unsigned u = __float_as_uint(f);
    unsigned r = u + 0x7FFFu + ((u >> 16) & 1u);   // round-to-nearest-even
    return (unsigned short)(r >> 16);
}
static __device__ __forceinline__ float bf2f(unsigned short b) {
    return __uint_as_float(((unsigned)b) << 16);
}
// fragment-ready layout: entity panel p=e>>5, k-slot q=k>>3:
//   u16 index = p*2048 + q*256 + (e&31)*8 + (k&7)
// so lane l's 8-bf16 MFMA fragment (entity=l&31, k=(l>>5)*8+j+16s) is one
// 16B load at short8-index  p*256 + (s*2+(l>>5))*32 + (l&31)  -> lane-consecutive.
static __device__ __forceinline__ size_t fragidx(int e, int k) {
    return (size_t)(e >> 5) * 2048 + (size_t)(k >> 3) * 256 + (e & 31) * 8 + (k & 7);
}

// ---------------------------------------------------------------------------
// prep: normalize codebook. cb fp32 (for gather) + double-normalized hi/lo
// bf16 fragments.
// ---------------------------------------------------------------------------
__global__ __launch_bounds__(256) void k_prep_cb(const float* __restrict__ cbin,
                                                 float* __restrict__ cb,
                                                 unsigned short* __restrict__ ch,
                                                 unsigned short* __restrict__ cl) {
    const int t = threadIdx.x;
    const int wv = t >> 6, lane = t & 63;
    const int code = blockIdx.x * 4 + wv;
    float v = cbin[(size_t)code * D + lane];
    float ss = v * v;
    #pragma unroll
    for (int off = 32; off; off >>= 1) ss += __shfl_xor(ss, off, 64);
    const float c1 = v / (sqrtf(ss) + EPSV);
    cb[(size_t)code * D + lane] = c1;
    float ss2 = c1 * c1;
    #pragma unroll
    for (int off = 32; off; off >>= 1) ss2 += __shfl_xor(ss2, off, 64);
    const float c2 = c1 / (sqrtf(ss2) + EPSV);
    const unsigned short h = f2bf(c2);
    const size_t fi = fragidx(code, lane);
    ch[fi] = h;
    cl[fi] = f2bf(c2 - bf2f(h));
}

// ---------------------------------------------------------------------------
// prep: normalize x -> xn (fp32, straight to d_out region 2) + hi/lo fragments
// ---------------------------------------------------------------------------
__global__ __launch_bounds__(256) void k_prep_x(const float* __restrict__ xin,
                                                float* __restrict__ xn,
                                                unsigned short* __restrict__ xh,
                                                unsigned short* __restrict__ xl) {
    const int t = threadIdx.x;
    const int wv = t >> 6, lane = t & 63;
    const int row = blockIdx.x * 4 + wv;
    float v = xin[(size_t)row * D + lane];
    float ss = v * v;
    #pragma unroll
    for (int off = 32; off; off >>= 1) ss += __shfl_xor(ss, off, 64);
    const float xv = v / (sqrtf(ss) + EPSV);
    xn[(size_t)row * D + lane] = xv;
    const unsigned short h = f2bf(xv);
    const size_t fi = fragidx(row, lane);
    xh[fi] = h;
    xl[fi] = f2bf(xv - bf2f(h));
}

// ---------------------------------------------------------------------------
// main: 128 rows x 128 codes per block, 4 waves (each: 32 rows x 128 codes).
// 3-term bf16 MFMA (32x32x16). dist quantized to 18 bits, packed (q<<14)|k:
// u32-min = argmin with lower-index tie-break. Track top-2 for margin flag.
// No LDS, no barriers; all loads coalesced from fragment-ready layouts.
// ---------------------------------------------------------------------------
__global__ __launch_bounds__(256, 3) void k_mfma(const unsigned short* __restrict__ xh,
                                                 const unsigned short* __restrict__ xl,
                                                 const unsigned short* __restrict__ ch,
                                                 const unsigned short* __restrict__ cl,
                                                 const int* __restrict__ mask,
                                                 const int* __restrict__ training,
                                                 unsigned* __restrict__ pk1,
                                                 unsigned* __restrict__ pk2,
                                                 int K, int ncb) {
    const int t = threadIdx.x;
    const int wv = t >> 6, lane = t & 63;
    const int lh = lane >> 5, lm = lane & 31;
    const int cbk = blockIdx.x % ncb;
    const int rb  = blockIdx.x / ncb;
    const int tr = training[0];

    const short8* xh8 = (const short8*)xh;
    const short8* xl8 = (const short8*)xl;
    const short8* ch8 = (const short8*)ch;
    const short8* cl8 = (const short8*)cl;

    // A fragments: 32 rows x 64 dims, hi+lo (held for the whole block)
    const int rp = rb * 4 + wv;                  // row panel of 32
    short8 ah[4], al[4];
    #pragma unroll
    for (int s = 0; s < 4; ++s) {
        const size_t ai = (size_t)rp * 256 + (s * 2 + lh) * 32 + lm;
        ah[s] = xh8[ai];
        al[s] = xl8[ai];
    }

    unsigned k1[16], k2[16];
    #pragma unroll
    for (int i = 0; i < 16; ++i) { k1[i] = 0xFFFFFFFFu; k2[i] = 0xFFFFFFFFu; }

    const int row0 = rb * 128 + wv * 32;
    const int* mb = mask + (size_t)row0 * K + cbk * 128 + lm;

    #pragma unroll
    for (int c = 0; c < 4; ++c) {
        const int cp = cbk * 4 + c;              // code panel of 32
        // mask loads for this panel (coalesced across lanes; row-strided regs)
        int mv[16];
        #pragma unroll
        for (int r = 0; r < 16; ++r) {
            const int row = (r & 3) + 8 * (r >> 2) + 4 * lh;
            mv[r] = mb[(size_t)row * K + c * 32];
        }
        short8 bh[4], bl[4];
        #pragma unroll
        for (int s = 0; s < 4; ++s) {
            const size_t bi = (size_t)cp * 256 + (s * 2 + lh) * 32 + lm;
            bh[s] = ch8[bi];
            bl[s] = cl8[bi];
        }
        f32x16 acc;
        #pragma unroll
        for (int i = 0; i < 16; ++i) acc[i] = 0.f;
        #pragma unroll
        for (int s = 0; s < 4; ++s) {
            acc = __builtin_amdgcn_mfma_f32_32x32x16_bf16(ah[s], bh[s], acc, 0, 0, 0);
            acc = __builtin_amdgcn_mfma_f32_32x32x16_bf16(ah[s], bl[s], acc, 0, 0, 0);
            acc = __builtin_amdgcn_mfma_f32_32x32x16_bf16(al[s], bh[s], acc, 0, 0, 0);
        }
        const unsigned kg = (unsigned)(cbk * 128 + c * 32 + lm);   // 14-bit code id
        #pragma unroll
        for (int r = 0; r < 16; ++r) {
            const float sim = acc[r];
            const float dist = (tr && mv[r] == 0) ? 2.0f : -sim;   // 2.0 > any -sim
            unsigned q = (unsigned)(int)fmaf(dist, 65536.0f, 131072.0f);
            q = q > 262143u ? 262143u : q;
            const unsigned key = (q << 14) | kg;
            const unsigned mx = k1[r] > key ? k1[r] : key;
            k1[r] = k1[r] < key ? k1[r] : key;
            k2[r] = k2[r] < mx ? k2[r] : mx;
        }
    }

    // reduce over the 32 codes held by this half-wave
    #pragma unroll
    for (int r = 0; r < 16; ++r) {
        unsigned a = k1[r], b = k2[r];
        #pragma unroll
        for (int off = 1; off < 32; off <<= 1) {
            const unsigned oa = (unsigned)__shfl_xor((int)a, off, 32);
            const unsigned ob = (unsigned)__shfl_xor((int)b, off, 32);
            const unsigned mx = a > oa ? a : oa;
            a = a < oa ? a : oa;
            const unsigned mn = b < ob ? b : ob;
            b = mn < mx ? mn : mx;
        }
        k1[r] = a; k2[r] = b;
    }
    if (lm == 0) {
        #pragma unroll
        for (int r = 0; r < 16; ++r) {
            const int row = row0 + (r & 3) + 8 * (r >> 2) + 4 * lh;
            pk1[(size_t)row * ncb + cbk] = k1[r];
            pk2[(size_t)row * ncb + cbk] = k2[r];
        }
    }
}

// ---------------------------------------------------------------------------
// combine 128 block-partials per row; flag rows with top-2 gap < 10 quanta
// ---------------------------------------------------------------------------
__global__ __launch_bounds__(256) void k_reduce2(const unsigned* __restrict__ pk1,
                                                 const unsigned* __restrict__ pk2,
                                                 int* __restrict__ bestidx,
                                                 int* __restrict__ fixlist,
                                                 int* __restrict__ fixcnt,
                                                 int ncb) {
    const int t = threadIdx.x;
    const int wv = t >> 6, lane = t & 63;
    const int row = blockIdx.x * 4 + wv;
    const unsigned* p1 = pk1 + (size_t)row * ncb;
    const unsigned* p2 = pk2 + (size_t)row * ncb;
    const unsigned a1 = p1[lane],      a2 = p2[lane];
    const unsigned b1 = p1[lane + 64], b2 = p2[lane + 64];
    unsigned mx = a1 > b1 ? a1 : b1;
    unsigned k1 = a1 < b1 ? a1 : b1;
    unsigned k2 = a2 < b2 ? a2 : b2;
    k2 = k2 < mx ? k2 : mx;
    #pragma unroll
    for (int off = 1; off < 64; off <<= 1) {
        const unsigned oa = (unsigned)__shfl_xor((int)k1, off, 64);
        const unsigned ob = (unsigned)__shfl_xor((int)k2, off, 64);
        mx = k1 > oa ? k1 : oa;
        k1 = k1 < oa ? k1 : oa;
        const unsigned mn = k2 < ob ? k2 : ob;
        k2 = mn < mx ? mn : mx;
    }
    if (lane == 0) {
        bestidx[row] = (int)(k1 & 16383u);
        if ((k2 >> 14) - (k1 >> 14) < 10u) {
            const int p = atomicAdd(fixcnt, 1);
            fixlist[p] = row;
        }
    }
}

// ---------------------------------------------------------------------------
// gather + write all outputs
// ---------------------------------------------------------------------------
__global__ __launch_bounds__(256) void k_out(const float* __restrict__ xn,
                                             const float* __restrict__ cb,
                                             const int* __restrict__ bestidx,
                                             float* __restrict__ out, int B) {
    const int t = threadIdx.x;
    const int wv = t >> 6, lane = t & 63;
    const int row = blockIdx.x * 4 + wv;
    const int bi = bestidx[row];
    const float zv  = cb[(size_t)bi * D + lane];
    const float xnv = xn[(size_t)row * D + lane];
    out[(size_t)row * D + lane] = xnv + (zv - xnv);                 // z_q
    out[(size_t)B * D + (size_t)row * D + lane] = zv;               // z
    if (lane == 0) out[(size_t)3 * B * D + row] = (float)bi;        // index
}

// ---------------------------------------------------------------------------
// exact fp32 rescan for flagged (near-tie) rows; overwrites their outputs
// ---------------------------------------------------------------------------
__global__ __launch_bounds__(256) void k_fix(const float* __restrict__ xn,
                                             const float* __restrict__ cb,
                                             const int* __restrict__ mask,
                                             const int* __restrict__ training,
                                             const int* __restrict__ fixlist,
                                             const int* __restrict__ fixcnt,
                                             float* __restrict__ out, int B, int K) {
    const int nf = *fixcnt;
    const int tr = training[0];
    __shared__ float sv[256];
    __shared__ int   si[256];
    const int t = threadIdx.x;
    for (int i = blockIdx.x; i < nf; i += gridDim.x) {
        const int row = fixlist[i];
        const float* xr = xn + (size_t)row * D;
        float b1 = FLT_MAX; int i1 = 0;
        for (int k = t; k < K; k += 256) {
            const float* cr = cb + (size_t)k * D;
            float s = 0.f;
            #pragma unroll
            for (int d = 0; d < D; ++d) s = fmaf(xr[d], cr[d], s);
            const int m = mask[(size_t)row * K + k];
            const float dist = (tr && m == 0) ? 1000000000.0f : -s;
            if (dist < b1) { b1 = dist; i1 = k; }
        }
        sv[t] = b1; si[t] = i1;
        __syncthreads();
        for (int s = 128; s; s >>= 1) {
            if (t < s) {
                const float ov = sv[t + s]; const int oi = si[t + s];
                if (ov < sv[t] || (ov == sv[t] && oi < si[t])) { sv[t] = ov; si[t] = oi; }
            }
            __syncthreads();
        }
        const int bi = si[0];
        if (t < 64) {
            const float zv  = cb[(size_t)bi * D + t];
            const float xnv = xr[t];
            out[(size_t)row * D + t] = xnv + (zv - xnv);
            out[(size_t)B * D + (size_t)row * D + t] = zv;
        }
        if (t == 0) out[(size_t)3 * B * D + row] = (float)bi;
        __syncthreads();
    }
}

extern "C" void kernel_launch(void* const* d_in, const int* in_sizes, int n_in,
                              void* d_out, int out_size, void* d_ws, size_t ws_size,
                              hipStream_t stream) {
    const float* x    = (const float*)d_in[0];
    const float* cbin = (const float*)d_in[1];
    const int* mask   = (const int*)d_in[2];
    const int* train  = (const int*)d_in[3];
    const int B = in_sizes[0] / D;   // 16384
    const int K = in_sizes[1] / D;   // 16384
    const int ncb = K / 128;         // 128 code-blocks
    float* out = (float*)d_out;
    float* out_xn = out + (size_t)2 * B * D;

    char* w = (char*)d_ws;
    float* cbw          = (float*)w;                               // 4 MB
    unsigned short* xhw = (unsigned short*)(w + (size_t)K * D * 4);
    unsigned short* xlw = xhw + (size_t)B * D;
    unsigned short* chw = xlw + (size_t)B * D;
    unsigned short* clw = chw + (size_t)K * D;
    unsigned* pk1       = (unsigned*)(clw + (size_t)K * D);        // 8 MB
    unsigned* pk2       = pk1 + (size_t)B * ncb;                   // 8 MB
    int* bestidx        = (int*)(pk2 + (size_t)B * ncb);
    int* fixlist        = bestidx + B;
    int* fixcnt         = fixlist + B;

    hipMemsetAsync(fixcnt, 0, sizeof(int), stream);

    k_prep_cb<<<K / 4, 256, 0, stream>>>(cbin, cbw, chw, clw);
    k_prep_x <<<B / 4, 256, 0, stream>>>(x, out_xn, xhw, xlw);
    k_mfma   <<<(B / 128) * ncb, 256, 0, stream>>>(xhw, xlw, chw, clw, mask, train,
                                                   pk1, pk2, K, ncb);
    k_reduce2<<<B / 4, 256, 0, stream>>>(pk1, pk2, bestidx, fixlist, fixcnt, ncb);
    k_out    <<<B / 4, 256, 0, stream>>>(out_xn, cbw, bestidx, out, B);
    k_fix    <<<256, 256, 0, stream>>>(out_xn, cbw, mask, train, fixlist, fixcnt,
                                       out, B, K);
}